// Round 6
// baseline (176.400 us; speedup 1.0000x reference)
//
#include <hip/hip_runtime.h>
#include <hip/hip_fp16.h>

#define M_TOK 4096
#define N_OUT 4096
#define K_IN  4096
#define BK 64
#define NNZ 32768

// 256x256 tile geometry
#define BM2 256
#define BN2 256

typedef __attribute__((ext_vector_type(8))) _Float16 half8;
typedef __attribute__((ext_vector_type(4))) float  f32x4;

// Single source of truth for the LDS XOR swizzle (rows are 128 B).
__device__ __forceinline__ int swz(int row, int byteoff) {
  return byteoff ^ ((row & 7) << 4);
}

// ---------------------------------------------------------------------------
// fp32 -> fp16 bulk convert (vectorized, grid-stride). n8 = elems/8.
// ---------------------------------------------------------------------------
__global__ __launch_bounds__(256) void cvt_kernel(
    const float* __restrict__ src, _Float16* __restrict__ dst, int n8) {
  const int stride = gridDim.x * blockDim.x;
  for (int i = blockIdx.x * blockDim.x + threadIdx.x; i < n8; i += stride) {
    f32x4 f0 = ((const f32x4*)src)[i * 2];
    f32x4 f1 = ((const f32x4*)src)[i * 2 + 1];
    half8 h;
    h[0] = (_Float16)f0[0]; h[1] = (_Float16)f0[1];
    h[2] = (_Float16)f0[2]; h[3] = (_Float16)f0[3];
    h[4] = (_Float16)f1[0]; h[5] = (_Float16)f1[1];
    h[6] = (_Float16)f1[2]; h[7] = (_Float16)f1[3];
    ((half8*)dst)[i] = h;
  }
}

// ---------------------------------------------------------------------------
// Scatter COO correction into the fp16 weight copy: Wh[idx] += v.
// 16-bit RMW via 32-bit atomicCAS (handles duplicate indices).
// ---------------------------------------------------------------------------
__global__ __launch_bounds__(256) void scatter_f16_kernel(
    _Float16* __restrict__ wh, const float* __restrict__ vals,
    const int* __restrict__ idxs) {
  const int i = blockIdx.x * blockDim.x + threadIdx.x;
  if (i >= NNZ) return;
  const int idx = idxs[i];
  const float v = vals[i];
  unsigned int* word =
      (unsigned int*)((unsigned long long)(wh + idx) & ~3ull);
  const bool hi = (idx & 1) != 0;
  unsigned int old = *word, assumed;
  do {
    assumed = old;
    unsigned short hbits =
        hi ? (unsigned short)(assumed >> 16) : (unsigned short)(assumed & 0xffff);
    _Float16 hv = __builtin_bit_cast(_Float16, hbits);
    unsigned short nh =
        __builtin_bit_cast(unsigned short, (_Float16)((float)hv + v));
    unsigned int neww = hi ? ((assumed & 0x0000ffffu) | ((unsigned int)nh << 16))
                           : ((assumed & 0xffff0000u) | nh);
    old = atomicCAS(word, assumed, neww);
  } while (old != assumed);
}

// ---------------------------------------------------------------------------
// 256x256-tile GEMM: out[m][n] = sum_k Xh[m][k] * Wh[n][k]   (both fp16)
// 8 waves (2M x 4N), per-wave 128x64 output, BK=64, double-buffered LDS
// (128 KiB), counted vmcnt(8) pipeline: loads for kt+1 issued at kt's head,
// never draining vmcnt to 0 in the main loop. LDS XOR-swizzled both sides.
// ---------------------------------------------------------------------------
__global__ __launch_bounds__(512, 2) void gemm256_kernel(
    const _Float16* __restrict__ Xh, const _Float16* __restrict__ Wh,
    float* __restrict__ out) {
  __shared__ __align__(16) _Float16 As[2][BM2 * BK];   // 2 x 32 KiB
  __shared__ __align__(16) _Float16 Bs[2][BN2 * BK];   // 2 x 32 KiB

  // bijective XCD swizzle (nwg = 256, divisible by 8)
  const int cpx = gridDim.x >> 3;
  const int bid = (blockIdx.x & 7) * cpx + (blockIdx.x >> 3);
  const int bm = bid >> 4;   // 16 row-blocks
  const int bn = bid & 15;   // 16 col-blocks

  const int tid  = threadIdx.x;
  const int lane = tid & 63;
  const int w    = tid >> 6;   // 0..7
  const int wm   = w >> 2;     // 0..1 (M)
  const int wn   = w & 3;      // 0..3 (N)
  const int lrow = lane & 15;
  const int lkg  = lane >> 4;

  // staging lane geometry: each gload_lds stages 64 rows (8 rows/wave),
  // lane -> row = rb + (lane>>3), 16B slot = lane&7; source slot inverse-
  // swizzled so linear LDS carries the (row&7)<<4 XOR pattern.
  const int srow = lane >> 3;
  const int slot = lane & 7;

  f32x4 acc[8][4] = {};

#define ISSUE_TILE(kt, buf)                                                    \
  {                                                                            \
    const int k0_ = (kt) * BK;                                                 \
    _Pragma("unroll") for (int i = 0; i < 4; ++i) {                            \
      const int rb   = i * 64 + w * 8;                                         \
      const int row  = rb + srow;                                              \
      const int cole = (slot ^ (row & 7)) * 8;                                 \
      const _Float16* srcA =                                                   \
          Xh + (size_t)(bm * BM2 + row) * K_IN + k0_ + cole;                   \
      const _Float16* srcB =                                                   \
          Wh + (size_t)(bn * BN2 + row) * K_IN + k0_ + cole;                   \
      __builtin_amdgcn_global_load_lds(                                        \
          (const __attribute__((address_space(1))) void*)srcA,                 \
          (__attribute__((address_space(3))) void*)&As[buf][rb * BK], 16, 0,   \
          0);                                                                  \
      __builtin_amdgcn_global_load_lds(                                        \
          (const __attribute__((address_space(1))) void*)srcB,                 \
          (__attribute__((address_space(3))) void*)&Bs[buf][rb * BK], 16, 0,   \
          0);                                                                  \
    }                                                                          \
  }

  ISSUE_TILE(0, 0);

  for (int kt = 0; kt < K_IN / BK; ++kt) {
    const int cur = kt & 1;

    // bar A: all waves done reading buf[cur^1]'s previous contents
    __builtin_amdgcn_s_barrier();

    if (kt + 1 < K_IN / BK) {
      ISSUE_TILE(kt + 1, cur ^ 1);
      __builtin_amdgcn_sched_barrier(0);
      asm volatile("s_waitcnt vmcnt(8)" ::: "memory");  // kt's loads landed
    } else {
      asm volatile("s_waitcnt vmcnt(0)" ::: "memory");
    }
    __builtin_amdgcn_sched_barrier(0);

    // bar B: combined with per-wave vmcnt above -> buf[cur] globally ready
    __builtin_amdgcn_s_barrier();

    // ---- 4 quadrant phases x 16 MFMA ----
#pragma unroll
    for (int q = 0; q < 4; ++q) {
      const int mh = q >> 1, nh = q & 1;
      half8 a[4][2], b[2][2];
#pragma unroll
      for (int mf = 0; mf < 4; ++mf) {
        const int row = wm * 128 + mh * 64 + mf * 16 + lrow;
#pragma unroll
        for (int kk = 0; kk < 2; ++kk)
          a[mf][kk] = *(const half8*)((const char*)&As[cur][0] + row * 128 +
                                      swz(row, kk * 64 + lkg * 16));
      }
#pragma unroll
      for (int nf = 0; nf < 2; ++nf) {
        const int row = wn * 64 + nh * 32 + nf * 16 + lrow;
#pragma unroll
        for (int kk = 0; kk < 2; ++kk)
          b[nf][kk] = *(const half8*)((const char*)&Bs[cur][0] + row * 128 +
                                      swz(row, kk * 64 + lkg * 16));
      }
      __builtin_amdgcn_s_setprio(1);
#pragma unroll
      for (int kk = 0; kk < 2; ++kk)
#pragma unroll
        for (int mf = 0; mf < 4; ++mf)
#pragma unroll
          for (int nf = 0; nf < 2; ++nf)
            acc[mh * 4 + mf][nh * 2 + nf] =
                __builtin_amdgcn_mfma_f32_16x16x32_f16(
                    a[mf][kk], b[nf][kk], acc[mh * 4 + mf][nh * 2 + nf], 0, 0,
                    0);
      __builtin_amdgcn_s_setprio(0);
      __builtin_amdgcn_sched_barrier(0);
    }
  }
#undef ISSUE_TILE

  // ---- epilogue: C/D layout col=lane&15, row=(lane>>4)*4+j ----
  const int crow0 = (lane >> 4) * 4;
  const int ccol  = lane & 15;
#pragma unroll
  for (int mf = 0; mf < 8; ++mf)
#pragma unroll
    for (int nf = 0; nf < 4; ++nf)
#pragma unroll
      for (int j = 0; j < 4; ++j) {
        const int gr = bm * BM2 + wm * 128 + mf * 16 + crow0 + j;
        const int gc = bn * BN2 + wn * 64 + nf * 16 + ccol;
        out[(size_t)gr * N_OUT + gc] = acc[mf][nf][j];
      }
}

// ---------------------------------------------------------------------------
// Fallback path (ws too small): fp32-staged 128^2 GEMM + sparse correction.
// ---------------------------------------------------------------------------
#define BM 128
#define BN 128
__global__ __launch_bounds__(256, 2) void gemm_f32src_kernel(
    const float* __restrict__ X, const float* __restrict__ W,
    float* __restrict__ out) {
  __shared__ __align__(16) _Float16 Asf[BM * BK];
  __shared__ __align__(16) _Float16 Bsf[BN * BK];
  const int cpx = gridDim.x >> 3;
  const int bid = (blockIdx.x & 7) * cpx + (blockIdx.x >> 3);
  const int bm = bid >> 5, bn = bid & 31;
  const int tid = threadIdx.x, lane = tid & 63, w = tid >> 6;
  const int wr = w >> 1, wc = w & 1, lrow = lane & 15, lkg = lane >> 4;
  f32x4 acc[4][4] = {};
  for (int ko = 0; ko < K_IN / BK; ++ko) {
    const int k0 = ko * BK;
#pragma unroll
    for (int p = 0; p < 4; ++p) {
      const int c = tid + p * 256, row = c >> 3, col8 = c & 7;
      const float* srcA = X + (size_t)(bm * BM + row) * K_IN + k0 + col8 * 8;
      const float* srcB = W + (size_t)(bn * BN + row) * K_IN + k0 + col8 * 8;
      f32x4 a0 = *(const f32x4*)srcA, a1 = *(const f32x4*)(srcA + 4);
      f32x4 b0 = *(const f32x4*)srcB, b1 = *(const f32x4*)(srcB + 4);
      half8 ha, hb;
#pragma unroll
      for (int j = 0; j < 4; ++j) {
        ha[j] = (_Float16)a0[j]; ha[j + 4] = (_Float16)a1[j];
        hb[j] = (_Float16)b0[j]; hb[j + 4] = (_Float16)b1[j];
      }
      *(half8*)((char*)Asf + row * 128 + swz(row, col8 * 16)) = ha;
      *(half8*)((char*)Bsf + row * 128 + swz(row, col8 * 16)) = hb;
    }
    __syncthreads();
#pragma unroll
    for (int kk = 0; kk < 2; ++kk) {
      const int kb = kk * 64 + lkg * 16;
      half8 a[4], b[4];
#pragma unroll
      for (int m = 0; m < 4; ++m) {
        const int row = wr * 64 + m * 16 + lrow;
        a[m] = *(const half8*)((const char*)Asf + row * 128 + swz(row, kb));
      }
#pragma unroll
      for (int n = 0; n < 4; ++n) {
        const int row = wc * 64 + n * 16 + lrow;
        b[n] = *(const half8*)((const char*)Bsf + row * 128 + swz(row, kb));
      }
#pragma unroll
      for (int m = 0; m < 4; ++m)
#pragma unroll
        for (int n = 0; n < 4; ++n)
          acc[m][n] = __builtin_amdgcn_mfma_f32_16x16x32_f16(
              a[m], b[n], acc[m][n], 0, 0, 0);
    }
    __syncthreads();
  }
  const int crow0 = (lane >> 4) * 4, ccol = lane & 15;
#pragma unroll
  for (int m = 0; m < 4; ++m)
#pragma unroll
    for (int n = 0; n < 4; ++n)
#pragma unroll
      for (int j = 0; j < 4; ++j)
        out[(size_t)(bm * BM + wr * 64 + m * 16 + crow0 + j) * N_OUT +
            bn * BN + wc * 64 + n * 16 + ccol] = acc[m][n][j];
}

__global__ __launch_bounds__(512) void sparse_kernel(
    const float* __restrict__ x, const float* __restrict__ vals,
    const int* __restrict__ idxs, float* __restrict__ out) {
  __shared__ float xrow[4096];
  __shared__ float accum[4096];
  const int b = blockIdx.x, tid = threadIdx.x;
  const float* xr = x + (size_t)b * 4096;
  for (int i = tid; i < 1024; i += 512) {
    ((float4*)xrow)[i]  = ((const float4*)xr)[i];
    ((float4*)accum)[i] = make_float4(0.f, 0.f, 0.f, 0.f);
  }
  __syncthreads();
  for (int it = 0; it < NNZ / (512 * 4); ++it) {
    const int i4 = it * 512 + tid;
    const int4   id = ((const int4*)idxs)[i4];
    const float4 v  = ((const float4*)vals)[i4];
    atomicAdd(&accum[id.x >> 12], v.x * xrow[id.x & 4095]);
    atomicAdd(&accum[id.y >> 12], v.y * xrow[id.y & 4095]);
    atomicAdd(&accum[id.z >> 12], v.z * xrow[id.z & 4095]);
    atomicAdd(&accum[id.w >> 12], v.w * xrow[id.w & 4095]);
  }
  __syncthreads();
  float* orow = out + (size_t)b * 4096;
  for (int i = tid; i < 1024; i += 512) {
    float4 o = ((float4*)orow)[i];
    const float4 a = ((const float4*)accum)[i];
    o.x += a.x; o.y += a.y; o.z += a.z; o.w += a.w;
    ((float4*)orow)[i] = o;
  }
}

extern "C" void kernel_launch(void* const* d_in, const int* in_sizes, int n_in,
                              void* d_out, int out_size, void* d_ws,
                              size_t ws_size, hipStream_t stream) {
  const float* x    = (const float*)d_in[0];
  const float* wgt  = (const float*)d_in[1];   // fp16 weights dequantized to fp32
  const float* vals = (const float*)d_in[2];
  const int*   idxs = (const int*)d_in[3];
  float*       out  = (float*)d_out;

  const size_t nelem  = (size_t)N_OUT * K_IN;          // 16.7M
  const size_t hbytes = nelem * sizeof(_Float16);       // 32 MiB

  if (ws_size >= 2 * hbytes) {
    _Float16* Xh = (_Float16*)d_ws;
    _Float16* Wh = (_Float16*)((char*)d_ws + hbytes);
    const int n8 = (int)(nelem / 8);
    cvt_kernel<<<2048, 256, 0, stream>>>(x, Xh, n8);
    cvt_kernel<<<2048, 256, 0, stream>>>(wgt, Wh, n8);
    scatter_f16_kernel<<<(NNZ + 255) / 256, 256, 0, stream>>>(Wh, vals, idxs);
    gemm256_kernel<<<(M_TOK / BM2) * (N_OUT / BN2), 512, 0, stream>>>(Xh, Wh,
                                                                      out);
  } else {
    gemm_f32src_kernel<<<(M_TOK / BM) * (N_OUT / BN), 256, 0, stream>>>(x, wgt,
                                                                        out);
    sparse_kernel<<<M_TOK, 512, 0, stream>>>(x, vals, idxs, out);
  }
}

// Round 7
// 169.996 us; speedup vs baseline: 1.0377x; 1.0377x over previous
//
#include <hip/hip_runtime.h>
#include <hip/hip_fp16.h>

#define M_TOK 4096
#define N_OUT 4096
#define K_IN  4096
#define BK 64
#define NNZ 32768

// 256x256 tile geometry
#define BM2 256
#define BN2 256

typedef __attribute__((ext_vector_type(8))) _Float16 half8;
typedef __attribute__((ext_vector_type(4))) float  f32x4;

// Single source of truth for the LDS XOR swizzle (rows are 128 B).
__device__ __forceinline__ int swz(int row, int byteoff) {
  return byteoff ^ ((row & 7) << 4);
}

// ---------------------------------------------------------------------------
// fp32 -> fp16 bulk convert (vectorized, grid-stride). n8 = elems/8.
// ---------------------------------------------------------------------------
__global__ __launch_bounds__(256) void cvt_kernel(
    const float* __restrict__ src, _Float16* __restrict__ dst, int n8) {
  const int stride = gridDim.x * blockDim.x;
  for (int i = blockIdx.x * blockDim.x + threadIdx.x; i < n8; i += stride) {
    f32x4 f0 = ((const f32x4*)src)[i * 2];
    f32x4 f1 = ((const f32x4*)src)[i * 2 + 1];
    half8 h;
    h[0] = (_Float16)f0[0]; h[1] = (_Float16)f0[1];
    h[2] = (_Float16)f0[2]; h[3] = (_Float16)f0[3];
    h[4] = (_Float16)f1[0]; h[5] = (_Float16)f1[1];
    h[6] = (_Float16)f1[2]; h[7] = (_Float16)f1[3];
    ((half8*)dst)[i] = h;
  }
}

// ---------------------------------------------------------------------------
// Scatter COO correction into the fp16 weight copy: Wh[idx] += v.
// 16-bit RMW via 32-bit atomicCAS (handles duplicate indices).
// ---------------------------------------------------------------------------
__global__ __launch_bounds__(256) void scatter_f16_kernel(
    _Float16* __restrict__ wh, const float* __restrict__ vals,
    const int* __restrict__ idxs) {
  const int i = blockIdx.x * blockDim.x + threadIdx.x;
  if (i >= NNZ) return;
  const int idx = idxs[i];
  const float v = vals[i];
  unsigned int* word =
      (unsigned int*)((unsigned long long)(wh + idx) & ~3ull);
  const bool hi = (idx & 1) != 0;
  unsigned int old = *word, assumed;
  do {
    assumed = old;
    unsigned short hbits =
        hi ? (unsigned short)(assumed >> 16) : (unsigned short)(assumed & 0xffff);
    _Float16 hv = __builtin_bit_cast(_Float16, hbits);
    unsigned short nh =
        __builtin_bit_cast(unsigned short, (_Float16)((float)hv + v));
    unsigned int neww = hi ? ((assumed & 0x0000ffffu) | ((unsigned int)nh << 16))
                           : ((assumed & 0xffff0000u) | nh);
    old = atomicCAS(word, assumed, neww);
  } while (old != assumed);
}

// ---------------------------------------------------------------------------
// 256x256-tile GEMM: out[m][n] = sum_k Xh[m][k] * Wh[n][k]   (both fp16)
// 8 waves (2M x 4N), per-wave 128x64 output, BK=64, double-buffered LDS
// (128 KiB), counted vmcnt(8) pipeline. kk-granular compute: each fragment
// is ds_read exactly ONCE per K-tile (24 reads/wave/tile) -- the round-6
// quadrant structure re-read each fragment 2x and was LDS-BW-bound.
// ---------------------------------------------------------------------------
__global__ __launch_bounds__(512, 2) void gemm256_kernel(
    const _Float16* __restrict__ Xh, const _Float16* __restrict__ Wh,
    float* __restrict__ out) {
  __shared__ __align__(16) _Float16 As[2][BM2 * BK];   // 2 x 32 KiB
  __shared__ __align__(16) _Float16 Bs[2][BN2 * BK];   // 2 x 32 KiB

  // bijective XCD swizzle (nwg = 256, divisible by 8)
  const int cpx = gridDim.x >> 3;
  const int bid = (blockIdx.x & 7) * cpx + (blockIdx.x >> 3);
  const int bm = bid >> 4;   // 16 row-blocks
  const int bn = bid & 15;   // 16 col-blocks

  const int tid  = threadIdx.x;
  const int lane = tid & 63;
  const int w    = tid >> 6;   // 0..7
  const int wm   = w >> 2;     // 0..1 (M)
  const int wn   = w & 3;      // 0..3 (N)
  const int lrow = lane & 15;
  const int lkg  = lane >> 4;

  // staging lane geometry: linear LDS dest, inverse-swizzled global source.
  const int srow = lane >> 3;
  const int slot = lane & 7;

  f32x4 acc[8][4] = {};

#define ISSUE_TILE(kt, buf)                                                    \
  {                                                                            \
    const int k0_ = (kt) * BK;                                                 \
    _Pragma("unroll") for (int i = 0; i < 4; ++i) {                            \
      const int rb   = i * 64 + w * 8;                                         \
      const int row  = rb + srow;                                              \
      const int cole = (slot ^ (row & 7)) * 8;                                 \
      const _Float16* srcA =                                                   \
          Xh + (size_t)(bm * BM2 + row) * K_IN + k0_ + cole;                   \
      const _Float16* srcB =                                                   \
          Wh + (size_t)(bn * BN2 + row) * K_IN + k0_ + cole;                   \
      __builtin_amdgcn_global_load_lds(                                        \
          (const __attribute__((address_space(1))) void*)srcA,                 \
          (__attribute__((address_space(3))) void*)&As[buf][rb * BK], 16, 0,   \
          0);                                                                  \
      __builtin_amdgcn_global_load_lds(                                        \
          (const __attribute__((address_space(1))) void*)srcB,                 \
          (__attribute__((address_space(3))) void*)&Bs[buf][rb * BK], 16, 0,   \
          0);                                                                  \
    }                                                                          \
  }

  ISSUE_TILE(0, 0);

  for (int kt = 0; kt < K_IN / BK; ++kt) {
    const int cur = kt & 1;

    // bar A: all waves done reading buf[cur^1]'s previous contents
    __builtin_amdgcn_s_barrier();

    if (kt + 1 < K_IN / BK) {
      ISSUE_TILE(kt + 1, cur ^ 1);
      __builtin_amdgcn_sched_barrier(0);
      asm volatile("s_waitcnt vmcnt(8)" ::: "memory");  // kt's loads landed
    } else {
      asm volatile("s_waitcnt vmcnt(0)" ::: "memory");
    }
    __builtin_amdgcn_sched_barrier(0);

    // bar B: combined with per-wave vmcnt above -> buf[cur] globally ready
    __builtin_amdgcn_s_barrier();

    // ---- 2 kk-phases: {8 A-reads + 4 B-reads, 32 MFMAs} each ----
#pragma unroll
    for (int kk = 0; kk < 2; ++kk) {
      const int kb = kk * 64 + lkg * 16;
      half8 a[8], b[4];
#pragma unroll
      for (int mf = 0; mf < 8; ++mf) {
        const int row = wm * 128 + mf * 16 + lrow;
        a[mf] = *(const half8*)((const char*)&As[cur][0] + row * 128 +
                                swz(row, kb));
      }
#pragma unroll
      for (int nf = 0; nf < 4; ++nf) {
        const int row = wn * 64 + nf * 16 + lrow;
        b[nf] = *(const half8*)((const char*)&Bs[cur][0] + row * 128 +
                                swz(row, kb));
      }
      __builtin_amdgcn_s_setprio(1);
#pragma unroll
      for (int mf = 0; mf < 8; ++mf)
#pragma unroll
        for (int nf = 0; nf < 4; ++nf)
          acc[mf][nf] = __builtin_amdgcn_mfma_f32_16x16x32_f16(
              a[mf], b[nf], acc[mf][nf], 0, 0, 0);
      __builtin_amdgcn_s_setprio(0);
      __builtin_amdgcn_sched_barrier(0);
    }
  }
#undef ISSUE_TILE

  // ---- epilogue: C/D layout col=lane&15, row=(lane>>4)*4+j ----
  const int crow0 = (lane >> 4) * 4;
  const int ccol  = lane & 15;
#pragma unroll
  for (int mf = 0; mf < 8; ++mf)
#pragma unroll
    for (int nf = 0; nf < 4; ++nf)
#pragma unroll
      for (int j = 0; j < 4; ++j) {
        const int gr = bm * BM2 + wm * 128 + mf * 16 + crow0 + j;
        const int gc = bn * BN2 + wn * 64 + nf * 16 + ccol;
        out[(size_t)gr * N_OUT + gc] = acc[mf][nf][j];
      }
}

// ---------------------------------------------------------------------------
// Fallback path (ws too small): fp32-staged 128^2 GEMM + sparse correction.
// ---------------------------------------------------------------------------
#define BM 128
#define BN 128
__global__ __launch_bounds__(256, 2) void gemm_f32src_kernel(
    const float* __restrict__ X, const float* __restrict__ W,
    float* __restrict__ out) {
  __shared__ __align__(16) _Float16 Asf[BM * BK];
  __shared__ __align__(16) _Float16 Bsf[BN * BK];
  const int cpx = gridDim.x >> 3;
  const int bid = (blockIdx.x & 7) * cpx + (blockIdx.x >> 3);
  const int bm = bid >> 5, bn = bid & 31;
  const int tid = threadIdx.x, lane = tid & 63, w = tid >> 6;
  const int wr = w >> 1, wc = w & 1, lrow = lane & 15, lkg = lane >> 4;
  f32x4 acc[4][4] = {};
  for (int ko = 0; ko < K_IN / BK; ++ko) {
    const int k0 = ko * BK;
#pragma unroll
    for (int p = 0; p < 4; ++p) {
      const int c = tid + p * 256, row = c >> 3, col8 = c & 7;
      const float* srcA = X + (size_t)(bm * BM + row) * K_IN + k0 + col8 * 8;
      const float* srcB = W + (size_t)(bn * BN + row) * K_IN + k0 + col8 * 8;
      f32x4 a0 = *(const f32x4*)srcA, a1 = *(const f32x4*)(srcA + 4);
      f32x4 b0 = *(const f32x4*)srcB, b1 = *(const f32x4*)(srcB + 4);
      half8 ha, hb;
#pragma unroll
      for (int j = 0; j < 4; ++j) {
        ha[j] = (_Float16)a0[j]; ha[j + 4] = (_Float16)a1[j];
        hb[j] = (_Float16)b0[j]; hb[j + 4] = (_Float16)b1[j];
      }
      *(half8*)((char*)Asf + row * 128 + swz(row, col8 * 16)) = ha;
      *(half8*)((char*)Bsf + row * 128 + swz(row, col8 * 16)) = hb;
    }
    __syncthreads();
#pragma unroll
    for (int kk = 0; kk < 2; ++kk) {
      const int kb = kk * 64 + lkg * 16;
      half8 a[4], b[4];
#pragma unroll
      for (int m = 0; m < 4; ++m) {
        const int row = wr * 64 + m * 16 + lrow;
        a[m] = *(const half8*)((const char*)Asf + row * 128 + swz(row, kb));
      }
#pragma unroll
      for (int n = 0; n < 4; ++n) {
        const int row = wc * 64 + n * 16 + lrow;
        b[n] = *(const half8*)((const char*)Bsf + row * 128 + swz(row, kb));
      }
#pragma unroll
      for (int m = 0; m < 4; ++m)
#pragma unroll
        for (int n = 0; n < 4; ++n)
          acc[m][n] = __builtin_amdgcn_mfma_f32_16x16x32_f16(
              a[m], b[n], acc[m][n], 0, 0, 0);
    }
    __syncthreads();
  }
  const int crow0 = (lane >> 4) * 4, ccol = lane & 15;
#pragma unroll
  for (int m = 0; m < 4; ++m)
#pragma unroll
    for (int n = 0; n < 4; ++n)
#pragma unroll
      for (int j = 0; j < 4; ++j)
        out[(size_t)(bm * BM + wr * 64 + m * 16 + crow0 + j) * N_OUT +
            bn * BN + wc * 64 + n * 16 + ccol] = acc[m][n][j];
}

__global__ __launch_bounds__(512) void sparse_kernel(
    const float* __restrict__ x, const float* __restrict__ vals,
    const int* __restrict__ idxs, float* __restrict__ out) {
  __shared__ float xrow[4096];
  __shared__ float accum[4096];
  const int b = blockIdx.x, tid = threadIdx.x;
  const float* xr = x + (size_t)b * 4096;
  for (int i = tid; i < 1024; i += 512) {
    ((float4*)xrow)[i]  = ((const float4*)xr)[i];
    ((float4*)accum)[i] = make_float4(0.f, 0.f, 0.f, 0.f);
  }
  __syncthreads();
  for (int it = 0; it < NNZ / (512 * 4); ++it) {
    const int i4 = it * 512 + tid;
    const int4   id = ((const int4*)idxs)[i4];
    const float4 v  = ((const float4*)vals)[i4];
    atomicAdd(&accum[id.x >> 12], v.x * xrow[id.x & 4095]);
    atomicAdd(&accum[id.y >> 12], v.y * xrow[id.y & 4095]);
    atomicAdd(&accum[id.z >> 12], v.z * xrow[id.z & 4095]);
    atomicAdd(&accum[id.w >> 12], v.w * xrow[id.w & 4095]);
  }
  __syncthreads();
  float* orow = out + (size_t)b * 4096;
  for (int i = tid; i < 1024; i += 512) {
    float4 o = ((float4*)orow)[i];
    const float4 a = ((const float4*)accum)[i];
    o.x += a.x; o.y += a.y; o.z += a.z; o.w += a.w;
    ((float4*)orow)[i] = o;
  }
}

extern "C" void kernel_launch(void* const* d_in, const int* in_sizes, int n_in,
                              void* d_out, int out_size, void* d_ws,
                              size_t ws_size, hipStream_t stream) {
  const float* x    = (const float*)d_in[0];
  const float* wgt  = (const float*)d_in[1];   // fp16 weights dequantized to fp32
  const float* vals = (const float*)d_in[2];
  const int*   idxs = (const int*)d_in[3];
  float*       out  = (float*)d_out;

  const size_t nelem  = (size_t)N_OUT * K_IN;          // 16.7M
  const size_t hbytes = nelem * sizeof(_Float16);       // 32 MiB

  if (ws_size >= 2 * hbytes) {
    _Float16* Xh = (_Float16*)d_ws;
    _Float16* Wh = (_Float16*)((char*)d_ws + hbytes);
    const int n8 = (int)(nelem / 8);
    cvt_kernel<<<2048, 256, 0, stream>>>(x, Xh, n8);
    cvt_kernel<<<2048, 256, 0, stream>>>(wgt, Wh, n8);
    scatter_f16_kernel<<<(NNZ + 255) / 256, 256, 0, stream>>>(Wh, vals, idxs);
    gemm256_kernel<<<(M_TOK / BM2) * (N_OUT / BN2), 512, 0, stream>>>(Xh, Wh,
                                                                      out);
  } else {
    gemm_f32src_kernel<<<(M_TOK / BM) * (N_OUT / BN), 256, 0, stream>>>(x, wgt,
                                                                        out);
    sparse_kernel<<<M_TOK, 512, 0, stream>>>(x, vals, idxs, out);
  }
}